// Round 1
// 1299.457 us; speedup vs baseline: 1.0831x; 1.0831x over previous
//
#include <hip/hip_runtime.h>
#include <hip/hip_bf16.h>
#include <math.h>

#define NPOS 4900
#define NG1  708
#define NG2  4192
#define INF  512
#define OUTF 256
#define JB   4904       // B' j-row count (rows 4900..4903 zeroed)
#define JS   384        // logits slab width
#define NSLAB 13        // ceil(4900/384)
#define LDS_KS 36       // k2: ushort k-stride (32 + 4 pad)
#define PCH   2508800   // k2 partial chunk stride in floats (512*4900)

typedef __attribute__((ext_vector_type(8))) short short8;
typedef __attribute__((ext_vector_type(16))) float f32x16;

// ---------------------------------------------------------------------------
// K0: rp = r @ Wr + br  (4x256); store S[0]=rp[ridx], S[1]=rp[2], S[2]=rp[3]
// ---------------------------------------------------------------------------
__global__ __launch_bounds__(256) void k0_rp(
    const float* __restrict__ r, const float* __restrict__ Wr,
    const float* __restrict__ br, const int* __restrict__ flagp,
    float* __restrict__ S)
{
    __shared__ float rsh[1024];
    int t = threadIdx.x;
    for (int i = t; i < 1024; i += 256) rsh[i] = r[i];
    __syncthreads();
    float a0 = 0.f, a1 = 0.f, a2 = 0.f, a3 = 0.f;
    for (int c = 0; c < 256; ++c) {
        float w = Wr[c * 256 + t];
        a0 += rsh[c] * w;
        a1 += rsh[256 + c] * w;
        a2 += rsh[512 + c] * w;
        a3 += rsh[768 + c] * w;
    }
    float b = br[t];
    a0 += b; a1 += b; a2 += b; a3 += b;
    int ridx = (flagp[0] != 0) ? 1 : 0;
    S[t]         = ridx ? a1 : a0;
    S[256 + t]   = a2;
    S[512 + t]   = a3;
}

// ---------------------------------------------------------------------------
// K1: fused projections hQ/hK/hV/H = feature @ {Wq,Wk,Wv,Ww} + bias
// ---------------------------------------------------------------------------
__global__ __launch_bounds__(256) void k1_proj(
    const float* __restrict__ feat,
    const float* __restrict__ Wq, const float* __restrict__ bq,
    const float* __restrict__ Wk, const float* __restrict__ bk,
    const float* __restrict__ Wv, const float* __restrict__ bv,
    const float* __restrict__ Ww, const float* __restrict__ bw,
    float* __restrict__ hQ, float* __restrict__ hK,
    float* __restrict__ hV, float* __restrict__ Hb)
{
    __shared__ float AT[16][68];    // [k][m]
    __shared__ float Bs[16][132];   // [k][n]
    int t = threadIdx.x;
    int mat = blockIdx.x >> 1;
    int n0  = (blockIdx.x & 1) * 128;
    int m0  = blockIdx.y * 64;
    const float* W; const float* bias; float* dst;
    switch (mat) {
        case 0:  W = Wq; bias = bq; dst = hQ; break;
        case 1:  W = Wk; bias = bk; dst = hK; break;
        case 2:  W = Wv; bias = bv; dst = hV; break;
        default: W = Ww; bias = bw; dst = Hb; break;
    }
    float acc[4][8];
#pragma unroll
    for (int i = 0; i < 4; ++i)
#pragma unroll
        for (int j = 0; j < 8; ++j) acc[i][j] = 0.f;
    int mg = (t >> 4) * 4, jg = (t & 15) * 8;
    int am = t & 63, ak = (t >> 6) * 4;
    int bkk = t >> 4, bn = (t & 15) * 8;
    for (int k0 = 0; k0 < INF; k0 += 16) {
        __syncthreads();
        {
            int row = m0 + am;
            float4 v = make_float4(0.f, 0.f, 0.f, 0.f);
            if (row < NPOS) v = *(const float4*)(feat + (size_t)row * INF + k0 + ak);
            AT[ak + 0][am] = v.x; AT[ak + 1][am] = v.y;
            AT[ak + 2][am] = v.z; AT[ak + 3][am] = v.w;
        }
        {
            const float* p = W + (size_t)(k0 + bkk) * OUTF + n0 + bn;
            float4 u0 = *(const float4*)p;
            float4 u1 = *(const float4*)(p + 4);
            *(float4*)&Bs[bkk][bn]     = u0;
            *(float4*)&Bs[bkk][bn + 4] = u1;
        }
        __syncthreads();
#pragma unroll
        for (int kk = 0; kk < 16; ++kk) {
            float4 a  = *(const float4*)&AT[kk][mg];
            float4 b0 = *(const float4*)&Bs[kk][jg];
            float4 b1 = *(const float4*)&Bs[kk][jg + 4];
            float av[4] = {a.x, a.y, a.z, a.w};
            float bv_[8] = {b0.x, b0.y, b0.z, b0.w, b1.x, b1.y, b1.z, b1.w};
#pragma unroll
            for (int i = 0; i < 4; ++i)
#pragma unroll
                for (int j = 0; j < 8; ++j) acc[i][j] += av[i] * bv_[j];
        }
    }
#pragma unroll
    for (int i = 0; i < 4; ++i) {
        int row = m0 + mg + i;
        if (row < NPOS) {
#pragma unroll
            for (int j = 0; j < 8; ++j) {
                int n = n0 + jg + j;
                dst[(size_t)row * OUTF + n] = acc[i][j] + bias[n];
            }
        }
    }
}

// ---------------------------------------------------------------------------
// split helpers (truncation split: x = hi(bf16) + lo(bf16), rel err ~2^-16)
// ---------------------------------------------------------------------------
__device__ __forceinline__ void split2(float x0, float x1,
                                       unsigned& hi, unsigned& lo)
{
    unsigned u0 = __float_as_uint(x0), u1 = __float_as_uint(x1);
    unsigned h0 = u0 & 0xFFFF0000u,   h1 = u1 & 0xFFFF0000u;
    float r0 = x0 - __uint_as_float(h0);
    float r1 = x1 - __uint_as_float(h1);
    hi = (h0 >> 16) | h1;
    lo = (__float_as_uint(r0) >> 16) | (__float_as_uint(r1) & 0xFFFF0000u);
}

__device__ __forceinline__ void split1(float x, unsigned short& hi, unsigned short& lo)
{
    unsigned u = __float_as_uint(x);
    unsigned h = u & 0xFFFF0000u;
    float r = x - __uint_as_float(h);
    hi = (unsigned short)(h >> 16);
    lo = (unsigned short)(__float_as_uint(r) >> 16);
}

__device__ __forceinline__ short8 ldfrag(const unsigned short* base, int row, int kuo)
{
    const unsigned long long* p =
        (const unsigned long long*)(base + row * LDS_KS + kuo);
    union { unsigned long long q[2]; short8 s; } u;
    u.q[0] = p[0];
    u.q[1] = p[1];
    return u.s;
}

__device__ __forceinline__ short8 ldfrag20(const unsigned short* base, int row, int kuo)
{
    const unsigned long long* p =
        (const unsigned long long*)(base + row * 20 + kuo);
    union { unsigned long long q[2]; short8 s; } u;
    u.q[0] = p[0];
    u.q[1] = p[1];
    return u.s;
}

// ---------------------------------------------------------------------------
// K2 (MFMA split-bf16, K-SPLIT): fp32 partials of
//   Bc[part][(h*2+g)*64+dd][j] = sum_k hK~*adj
// blockIdx.z = chunk: 0 -> part0 [0,708); 1..3 -> part1 [0,1408),[1408,2816),
// [2816,4192). Partials: chunk0 -> P0, chunks 1..3 -> P1 + (c-1)*PCH.
// Occupancy fix: 1232 blocks (~4.8/CU) vs old 616 with a 308-block tail.
// split-bf16 conversion + transpose moved to k2_reduce.
// ---------------------------------------------------------------------------
__global__ __launch_bounds__(256) void k2_mfma(
    const float* __restrict__ hK, const float* __restrict__ adj,
    const float* __restrict__ S,
    float* __restrict__ P0, float* __restrict__ P1)
{
    __shared__ unsigned short sAh[128 * LDS_KS];
    __shared__ unsigned short sAl[128 * LDS_KS];
    __shared__ unsigned short sBh[64 * LDS_KS];
    __shared__ unsigned short sBl[64 * LDS_KS];

    int t = threadIdx.x;
    int j0 = blockIdx.x * 64;
    int h  = blockIdx.y;
    int chunk = blockIdx.z;
    int part = (chunk == 0) ? 0 : 1;
    int kbeg = (chunk <= 1) ? 0 : (chunk - 1) * 1408;
    int kend = (chunk == 0) ? NG1 : ((chunk == 3) ? NG2 : chunk * 1408);
    int L = part ? NG2 : NG1;
    const float* kflat = hK + (part ? (size_t)NG1 * OUTF : 0);
    int rowoff = part ? NG1 : 0;
    float* Pout = chunk ? (P1 + (size_t)(chunk - 1) * PCH) : P0;

    int dd = t & 63;          // staging lane: dd for A, n for B
    int kg = t >> 6;          // k-group 0..3 (== wave id)
    int jcol = j0 + dd;

    float sc[2][4];
#pragma unroll
    for (int g = 0; g < 2; ++g)
#pragma unroll
        for (int c = 0; c < 4; ++c)
            sc[g][c] = 0.5f * S[(g + part) * 256 + c * 64 + dd];

    f32x16 acc0, acc1;
#pragma unroll
    for (int i = 0; i < 16; ++i) { acc0[i] = 0.f; acc1[i] = 0.f; }

    int lane = t & 63;
    int half = lane >> 5;
    int ml = lane & 31;
    int arow = kg * 32 + ml;

    unsigned* uAh = (unsigned*)sAh;
    unsigned* uAl = (unsigned*)sAl;
    unsigned* uBh = (unsigned*)sBh;
    unsigned* uBl = (unsigned*)sBl;

    int ks0 = kbeg >> 5;
    int ks1 = (kend + 31) >> 5;
    for (int ks = ks0; ks < ks1; ++ks) {
        int k0 = ks * 32;
        float xa[8], xb[8];
#pragma unroll
        for (int i = 0; i < 8; ++i) {
            int kv = k0 + kg * 8 + i;
            bool okk = (kv < kend);
            xa[i] = okk ? kflat[(size_t)(h * L + kv) * 64 + dd] : 0.f;
            xb[i] = (okk && jcol < NPOS)
                        ? adj[(size_t)(rowoff + kv) * NPOS + jcol] : 0.f;
        }
        unsigned hA0[4], lA0[4], hA1[4], lA1[4], hB[4], lB[4];
#pragma unroll
        for (int i = 0; i < 8; i += 2) {
            float a0 = xa[i] * sc[0][i & 3];
            float a1 = xa[i + 1] * sc[0][(i + 1) & 3];
            split2(a0, a1, hA0[i >> 1], lA0[i >> 1]);
            float c0 = xa[i] * sc[1][i & 3];
            float c1 = xa[i + 1] * sc[1][(i + 1) & 3];
            split2(c0, c1, hA1[i >> 1], lA1[i >> 1]);
            split2(xb[i], xb[i + 1], hB[i >> 1], lB[i >> 1]);
        }
        __syncthreads();
        {
            int b0 = dd * 18 + kg * 4;
            int b1 = (64 + dd) * 18 + kg * 4;
            *(uint2*)(uAh + b0)     = make_uint2(hA0[0], hA0[1]);
            *(uint2*)(uAh + b0 + 2) = make_uint2(hA0[2], hA0[3]);
            *(uint2*)(uAl + b0)     = make_uint2(lA0[0], lA0[1]);
            *(uint2*)(uAl + b0 + 2) = make_uint2(lA0[2], lA0[3]);
            *(uint2*)(uAh + b1)     = make_uint2(hA1[0], hA1[1]);
            *(uint2*)(uAh + b1 + 2) = make_uint2(hA1[2], hA1[3]);
            *(uint2*)(uAl + b1)     = make_uint2(lA1[0], lA1[1]);
            *(uint2*)(uAl + b1 + 2) = make_uint2(lA1[2], lA1[3]);
            *(uint2*)(uBh + b0)     = make_uint2(hB[0], hB[1]);
            *(uint2*)(uBh + b0 + 2) = make_uint2(hB[2], hB[3]);
            *(uint2*)(uBl + b0)     = make_uint2(lB[0], lB[1]);
            *(uint2*)(uBl + b0 + 2) = make_uint2(lB[2], lB[3]);
        }
        __syncthreads();
#pragma unroll
        for (int kq = 0; kq < 2; ++kq) {
            int kuo = kq * 16 + half * 8;
            short8 aH = ldfrag(sAh, arow, kuo);
            short8 aL = ldfrag(sAl, arow, kuo);
            short8 b0H = ldfrag(sBh, ml, kuo);
            short8 b0L = ldfrag(sBl, ml, kuo);
            short8 b1H = ldfrag(sBh, 32 + ml, kuo);
            short8 b1L = ldfrag(sBl, 32 + ml, kuo);
            acc0 = __builtin_amdgcn_mfma_f32_32x32x16_bf16(aH, b0H, acc0, 0, 0, 0);
            acc0 = __builtin_amdgcn_mfma_f32_32x32x16_bf16(aH, b0L, acc0, 0, 0, 0);
            acc0 = __builtin_amdgcn_mfma_f32_32x32x16_bf16(aL, b0H, acc0, 0, 0, 0);
            acc1 = __builtin_amdgcn_mfma_f32_32x32x16_bf16(aH, b1H, acc1, 0, 0, 0);
            acc1 = __builtin_amdgcn_mfma_f32_32x32x16_bf16(aH, b1L, acc1, 0, 0, 0);
            acc1 = __builtin_amdgcn_mfma_f32_32x32x16_bf16(aL, b1H, acc1, 0, 0, 0);
        }
    }

    // epilogue: coalesced fp32 partial store, rows (h*2+g)*64+ddm, cols j
    int col0 = j0 + ml;        // <= 4895 < NPOS always
    int col1 = j0 + 32 + ml;   // may exceed
#pragma unroll
    for (int reg = 0; reg < 16; ++reg) {
        int m = kg * 32 + (reg & 3) + 8 * (reg >> 2) + 4 * half;
        int g = m >> 6, ddm = m & 63;
        size_t rb = (size_t)((h * 2 + g) * 64 + ddm) * NPOS;
        Pout[rb + col0] = acc0[reg];
        if (col1 < NPOS) Pout[rb + col1] = acc1[reg];
    }
}

// ---------------------------------------------------------------------------
// K2R: reduce part1 chunks + split-bf16 + transpose to B' planes
//   Bhi/Blo[(g*4+h)][j][k], k = part*64+dd.  Rows j in [4900,4904) zeroed.
// grid (20 j-tiles of 256, 8 gh planes, 8 k-groups of 16). Reads coalesced
// along j; each thread writes 32B (2x uint4) per plane at its own j row
// (L2 write-combines lines across the k-groups).
// ---------------------------------------------------------------------------
__global__ __launch_bounds__(256) void k2_reduce(
    const float* __restrict__ P0, const float* __restrict__ P1,
    unsigned short* __restrict__ Bhi, unsigned short* __restrict__ Blo)
{
    int t = threadIdx.x;
    int j = blockIdx.x * 256 + t;
    if (j >= JB) return;
    int p = blockIdx.y;               // plane = g*4+h (k3a layout)
    int g = p >> 2, h = p & 3;
    int kg = blockIdx.z;              // 16 k-values each
    int k0 = kg * 16;
    int rowb = (h * 2 + g) * 64;

    unsigned short hi[16], lo[16];
    if (j < NPOS) {
        if (k0 < 64) {
            // part0: single chunk
#pragma unroll
            for (int i = 0; i < 16; ++i) {
                float v = P0[(size_t)(rowb + k0 + i) * NPOS + j];
                split1(v, hi[i], lo[i]);
            }
        } else {
            // part1: sum of 3 chunks
#pragma unroll
            for (int i = 0; i < 16; ++i) {
                size_t off = (size_t)(rowb + (k0 - 64) + i) * NPOS + j;
                float v = P1[off] + P1[off + PCH] + P1[off + 2 * (size_t)PCH];
                split1(v, hi[i], lo[i]);
            }
        }
    } else {
#pragma unroll
        for (int i = 0; i < 16; ++i) { hi[i] = 0; lo[i] = 0; }
    }
    size_t base = ((size_t)p * JB + j) * 128 + k0;
    union { unsigned short us[16]; uint4 v[2]; } uh, ul;
#pragma unroll
    for (int i = 0; i < 16; ++i) { uh.us[i] = hi[i]; ul.us[i] = lo[i]; }
    *(uint4*)(Bhi + base)     = uh.v[0];
    *(uint4*)(Bhi + base + 8) = uh.v[1];
    *(uint4*)(Blo + base)     = ul.v[0];
    *(uint4*)(Blo + base + 8) = ul.v[1];
}

// ---------------------------------------------------------------------------
// K3a (MFMA split-bf16): LG[h][pos][jloc] = Q~[h,pos][0:128] . B'[gh][j][0:128]
// Tile M=128 q x N=128 j x K=128.  4 waves in 2x2, each wave 2m x 2n 32-tiles.
// A staged from hQ*S with on-the-fly split; B staged as ushort copies from B'.
// LDS rows: 16 k-ushorts @ stride 20 (2-way bank alias = free).
// ---------------------------------------------------------------------------
__global__ __launch_bounds__(256) void k3a_mfma(
    const float* __restrict__ hQ, const float* __restrict__ S,
    const unsigned short* __restrict__ Bhi, const unsigned short* __restrict__ Blo,
    float* __restrict__ LG, int j0)
{
    __shared__ __align__(16) unsigned short sA[2][128 * 20];  // [hi/lo][m][k16]
    __shared__ __align__(16) unsigned short sB[2][128 * 20];  // [hi/lo][j][k16]

    int t = threadIdx.x;
    int n0 = blockIdx.x * 128;       // 0,128,256 within slab
    int y = blockIdx.y;              // 156 = 4h * 39
    int h = y / 39, rr = y % 39;
    int g, tile;
    if (rr < 6) { g = 0; tile = rr; } else { g = 1; tile = rr - 6; }
    int Lg = g ? NG2 : NG1;
    int vbase = g ? NG1 * OUTF : 0;
    int posbase = g ? NG1 : 0;
    int q0 = tile * 128;

    int w = t >> 6, lane = t & 63;
    int half = lane >> 5, ml = lane & 31;
    int wm = w >> 1, wn = w & 1;

    f32x16 acc[2][2];
#pragma unroll
    for (int i = 0; i < 2; ++i)
#pragma unroll
        for (int j = 0; j < 2; ++j)
#pragma unroll
            for (int r = 0; r < 16; ++r) acc[i][j][r] = 0.f;

    // staging coords
    int mA = t >> 1, khA = t & 1;            // A: row m, k-half
    int jB = t & 127, plB = t >> 7;          // B: row j, plane
    size_t bplaneoff = (size_t)(g * 4 + h) * JB * 128;
    const unsigned short* bsrc = (plB ? Blo : Bhi) + bplaneoff;
    int jglob = j0 + n0 + jB;

    for (int kf = 0; kf < 8; ++kf) {
        int p = kf >> 2;
        int dA = (kf & 3) * 16 + khA * 8;    // d within 64-half
        // --- global prefetch ---
        float x[8];
        {
            int ql = q0 + mA;
            if (ql < Lg) {
                const float* qp = hQ + vbase + (size_t)(h * Lg + ql) * 64 + dA;
                const float* sp = S + (g + p) * 256 + (ql & 3) * 64 + dA;
                float4 q0v = ((const float4*)qp)[0];
                float4 q1v = ((const float4*)qp)[1];
                float4 s0v = ((const float4*)sp)[0];
                float4 s1v = ((const float4*)sp)[1];
                x[0] = q0v.x * s0v.x; x[1] = q0v.y * s0v.y;
                x[2] = q0v.z * s0v.z; x[3] = q0v.w * s0v.w;
                x[4] = q1v.x * s1v.x; x[5] = q1v.y * s1v.y;
                x[6] = q1v.z * s1v.z; x[7] = q1v.w * s1v.w;
            } else {
#pragma unroll
                for (int i = 0; i < 8; ++i) x[i] = 0.f;
            }
        }
        uint4 b0 = make_uint4(0, 0, 0, 0), b1 = make_uint4(0, 0, 0, 0);
        if (jglob < JB) {
            const uint4* bp = (const uint4*)(bsrc + (size_t)jglob * 128 + kf * 16);
            b0 = bp[0];
            b1 = bp[1];
        }
        unsigned hiA[4], loA[4];
#pragma unroll
        for (int i = 0; i < 4; ++i)
            split2(x[2 * i], x[2 * i + 1], hiA[i], loA[i]);

        __syncthreads();   // prev frag reads done
        {
            unsigned* pAh = (unsigned*)(sA[0] + mA * 20 + khA * 8);
            unsigned* pAl = (unsigned*)(sA[1] + mA * 20 + khA * 8);
            *(uint2*)pAh       = make_uint2(hiA[0], hiA[1]);
            *(uint2*)(pAh + 2) = make_uint2(hiA[2], hiA[3]);
            *(uint2*)pAl       = make_uint2(loA[0], loA[1]);
            *(uint2*)(pAl + 2) = make_uint2(loA[2], loA[3]);
            unsigned* pB = (unsigned*)(sB[plB] + jB * 20);
            *(uint2*)pB       = make_uint2(b0.x, b0.y);
            *(uint2*)(pB + 2) = make_uint2(b0.z, b0.w);
            *(uint2*)(pB + 4) = make_uint2(b1.x, b1.y);
            *(uint2*)(pB + 6) = make_uint2(b1.z, b1.w);
        }
        __syncthreads();   // staging visible

        short8 aH[2], aL[2], bH[2], bL[2];
#pragma unroll
        for (int i = 0; i < 2; ++i) {
            int mrow = (2 * wm + i) * 32 + ml;
            aH[i] = ldfrag20(sA[0], mrow, half * 8);
            aL[i] = ldfrag20(sA[1], mrow, half * 8);
            int nrow = (2 * wn + i) * 32 + ml;
            bH[i] = ldfrag20(sB[0], nrow, half * 8);
            bL[i] = ldfrag20(sB[1], nrow, half * 8);
        }
#pragma unroll
        for (int mi = 0; mi < 2; ++mi)
#pragma unroll
            for (int ni = 0; ni < 2; ++ni) {
                acc[mi][ni] = __builtin_amdgcn_mfma_f32_32x32x16_bf16(aH[mi], bH[ni], acc[mi][ni], 0, 0, 0);
                acc[mi][ni] = __builtin_amdgcn_mfma_f32_32x32x16_bf16(aH[mi], bL[ni], acc[mi][ni], 0, 0, 0);
                acc[mi][ni] = __builtin_amdgcn_mfma_f32_32x32x16_bf16(aL[mi], bH[ni], acc[mi][ni], 0, 0, 0);
            }
    }

    // epilogue: C/D layout col=lane&31, row=(reg&3)+8*(reg>>2)+4*(lane>>5)
#pragma unroll
    for (int mi = 0; mi < 2; ++mi) {
        int mtile = (2 * wm + mi) * 32;
#pragma unroll
        for (int reg = 0; reg < 16; ++reg) {
            int mloc = mtile + (reg & 3) + 8 * (reg >> 2) + 4 * half;
            int ql = q0 + mloc;
            if (ql < Lg) {
                float* dst = LG + ((size_t)h * NPOS + posbase + ql) * JS + n0;
#pragma unroll
                for (int ni = 0; ni < 2; ++ni) {
                    int nloc = (2 * wn + ni) * 32 + ml;
                    dst[nloc] = acc[mi][ni][reg];
                }
            }
        }
    }
}

// ---------------------------------------------------------------------------
// K3b: PV slab GEMM, ALL 4 heads per block (LG read exactly once).
// ---------------------------------------------------------------------------
__global__ __launch_bounds__(256) void k3b_pv(
    const float* __restrict__ LG, const float* __restrict__ hV,
    float* __restrict__ mpart, int j0, int first)
{
    __shared__ float Asm[4][16][34];   // [h][jj][pos]  alpha
    __shared__ float Bsv[16][264];     // [jj][ch]      V
    int t = threadIdx.x;
    int m0 = blockIdx.x * 32;
    int ks = blockIdx.y;
    int jbase = ks * 192;

    float acc[2][16];
#pragma unroll
    for (int i = 0; i < 2; ++i)
#pragma unroll
        for (int j = 0; j < 16; ++j) acc[i][j] = 0.f;
    int pos2 = (t & 15) * 2;
    int ch16 = (t >> 4) * 16;
    int hch  = ch16 >> 6;
    int sj = t & 15, sp = t >> 4;

    for (int kc = 0; kc < 192; kc += 16) {
        __syncthreads();
#pragma unroll
        for (int i = 0; i < 4; ++i) {
            int s = t + i * 256;
            int jj = s >> 6, c4 = (s & 63) * 4;
            int h = c4 >> 6, d = c4 & 63;
            int jglob = j0 + jbase + kc + jj;
            float4 x = make_float4(0.f, 0.f, 0.f, 0.f);
            if (jglob < NPOS)
                x = *(const float4*)(hV + ((size_t)h * NPOS + jglob) * 64 + d);
            *(float4*)&Bsv[jj][c4] = x;
        }
#pragma unroll
        for (int i = 0; i < 2; ++i) {
            int posl = sp + 16 * i;
            int pos = m0 + posl;
            int jglob = j0 + jbase + kc + sj;
            float v0 = 0.f, v1 = 0.f, v2 = 0.f, v3 = 0.f;
            if (pos < NPOS) {
                size_t base = (size_t)pos * JS + jbase + kc + sj;
                v0 = LG[base];
                v1 = LG[(size_t)NPOS * JS + base];
                v2 = LG[(size_t)2 * NPOS * JS + base];
                v3 = LG[(size_t)3 * NPOS * JS + base];
            }
            float mx = fmaxf(fmaxf(v0, v1), fmaxf(v2, v3));
            float e0 = __expf(v0 - mx), e1 = __expf(v1 - mx);
            float e2 = __expf(v2 - mx), e3 = __expf(v3 - mx);
            float inv = 1.0f / (e0 + e1 + e2 + e3);
            bool ok = (pos < NPOS) && (jglob < NPOS);
            float z = ok ? inv : 0.f;
            Asm[0][sj][posl] = e0 * z;
            Asm[1][sj][posl] = e1 * z;
            Asm[2][sj][posl] = e2 * z;
            Asm[3][sj][posl] = e3 * z;
        }
        __syncthreads();
#pragma unroll
        for (int kk = 0; kk < 16; ++kk) {
            float2 a = *(const float2*)&Asm[hch][kk][pos2];
            float4 b0 = *(const float4*)&Bsv[kk][ch16 + 0];
            float4 b1 = *(const float4*)&Bsv[kk][ch16 + 4];
            float4 b2 = *(const float4*)&Bsv[kk][ch16 + 8];
            float4 b3 = *(const float4*)&Bsv[kk][ch16 + 12];
            float bv_[16] = {b0.x, b0.y, b0.z, b0.w, b1.x, b1.y, b1.z, b1.w,
                             b2.x, b2.y, b2.z, b2.w, b3.x, b3.y, b3.z, b3.w};
#pragma unroll
            for (int j = 0; j < 16; ++j) {
                acc[0][j] += a.x * bv_[j];
                acc[1][j] += a.y * bv_[j];
            }
        }
    }
#pragma unroll
    for (int i = 0; i < 2; ++i) {
        int pos = m0 + pos2 + i;
        if (pos < NPOS) {
            float* pp = mpart + ((size_t)ks * NPOS + pos) * OUTF + ch16;
#pragma unroll
            for (int c = 0; c < 16; c += 4) {
                float4 prev = first ? make_float4(0.f, 0.f, 0.f, 0.f)
                                    : *(const float4*)(pp + c);
                *(float4*)(pp + c) = make_float4(prev.x + acc[i][c + 0],
                                                 prev.y + acc[i][c + 1],
                                                 prev.z + acc[i][c + 2],
                                                 prev.w + acc[i][c + 3]);
            }
        }
    }
}

// ---------------------------------------------------------------------------
// E1: m = mpart0+mpart1; relu; ln1; write concat buffer [H | ln1(relu(m))]
// ---------------------------------------------------------------------------
__global__ __launch_bounds__(256) void e1_relu_ln(
    const float* __restrict__ mpart, const float* __restrict__ Hb,
    const float* __restrict__ g1, const float* __restrict__ b1,
    float* __restrict__ cc)
{
    int w = threadIdx.x >> 6, lane = threadIdx.x & 63;
    int row = blockIdx.x * 4 + w;
    int c = lane * 4;
    float4 x0 = *(const float4*)(mpart + (size_t)row * OUTF + c);
    float4 x1 = *(const float4*)(mpart + (size_t)NPOS * OUTF + (size_t)row * OUTF + c);
    float x[4] = { fmaxf(x0.x + x1.x, 0.f), fmaxf(x0.y + x1.y, 0.f),
                   fmaxf(x0.z + x1.z, 0.f), fmaxf(x0.w + x1.w, 0.f) };
    float s = x[0] + x[1] + x[2] + x[3];
#pragma unroll
    for (int m = 32; m > 0; m >>= 1) s += __shfl_xor(s, m, 64);
    float mu = s * (1.0f / 256.0f);
    float vs = 0.f;
#pragma unroll
    for (int i = 0; i < 4; ++i) { float d = x[i] - mu; vs += d * d; }
#pragma unroll
    for (int m = 32; m > 0; m >>= 1) vs += __shfl_xor(vs, m, 64);
    float rs = rsqrtf(vs * (1.0f / 256.0f) + 1e-5f);
    float4 y;
    y.x = (x[0] - mu) * rs * g1[c + 0] + b1[c + 0];
    y.y = (x[1] - mu) * rs * g1[c + 1] + b1[c + 1];
    y.z = (x[2] - mu) * rs * g1[c + 2] + b1[c + 2];
    y.w = (x[3] - mu) * rs * g1[c + 3] + b1[c + 3];
    *(float4*)(cc + (size_t)row * INF + OUTF + c) = y;
    float4 hh = *(const float4*)(Hb + (size_t)row * OUTF + c);
    *(float4*)(cc + (size_t)row * INF + c) = hh;
}

// ---------------------------------------------------------------------------
// E2: beta = sigmoid(cc @ Wbeta + bbeta); out = beta*m1 + (1-beta)*H
// ---------------------------------------------------------------------------
__global__ __launch_bounds__(256) void e2_beta(
    const float* __restrict__ cc, const float* __restrict__ Wb,
    const float* __restrict__ bb, float* __restrict__ outb)
{
    __shared__ float AT[16][68];
    __shared__ float Bs[16][132];
    int t = threadIdx.x;
    int n0 = blockIdx.x * 128;
    int m0 = blockIdx.y * 64;
    float acc[4][8];
#pragma unroll
    for (int i = 0; i < 4; ++i)
#pragma unroll
        for (int j = 0; j < 8; ++j) acc[i][j] = 0.f;
    int mg = (t >> 4) * 4, jg = (t & 15) * 8;
    int am = t & 63, ak = (t >> 6) * 4;
    int bkk = t >> 4, bn = (t & 15) * 8;
    for (int k0 = 0; k0 < INF; k0 += 16) {
        __syncthreads();
        {
            int row = m0 + am;
            float4 v = make_float4(0.f, 0.f, 0.f, 0.f);
            if (row < NPOS) v = *(const float4*)(cc + (size_t)row * INF + k0 + ak);
            AT[ak + 0][am] = v.x; AT[ak + 1][am] = v.y;
            AT[ak + 2][am] = v.z; AT[ak + 3][am] = v.w;
        }
        {
            const float* p = Wb + (size_t)(k0 + bkk) * OUTF + n0 + bn;
            float4 u0 = *(const float4*)p;
            float4 u1 = *(const float4*)(p + 4);
            *(float4*)&Bs[bkk][bn]     = u0;
            *(float4*)&Bs[bkk][bn + 4] = u1;
        }
        __syncthreads();
#pragma unroll
        for (int kk = 0; kk < 16; ++kk) {
            float4 a  = *(const float4*)&AT[kk][mg];
            float4 b0 = *(const float4*)&Bs[kk][jg];
            float4 b1 = *(const float4*)&Bs[kk][jg + 4];
            float av[4] = {a.x, a.y, a.z, a.w};
            float bv_[8] = {b0.x, b0.y, b0.z, b0.w, b1.x, b1.y, b1.z, b1.w};
#pragma unroll
            for (int i = 0; i < 4; ++i)
#pragma unroll
                for (int j = 0; j < 8; ++j) acc[i][j] += av[i] * bv_[j];
        }
    }
#pragma unroll
    for (int i = 0; i < 4; ++i) {
        int row = m0 + mg + i;
        if (row < NPOS) {
#pragma unroll
            for (int j = 0; j < 8; ++j) {
                int n = n0 + jg + j;
                float x = acc[i][j] + bb[n];
                float sg = 1.0f / (1.0f + __expf(-x));
                float m1v = cc[(size_t)row * INF + OUTF + n];
                float Hv  = cc[(size_t)row * INF + n];
                outb[(size_t)row * OUTF + n] = sg * m1v + (1.0f - sg) * Hv;
            }
        }
    }
}

// ---------------------------------------------------------------------------
// E3: t = out @ w1 + b1 ; ln2(eps=1e-6) ; tanh -> h2.
// ---------------------------------------------------------------------------
__global__ __launch_bounds__(256) void e3_w1_ln2(
    const float* __restrict__ outb, const float* __restrict__ w1,
    const float* __restrict__ b1v, const float* __restrict__ g2,
    const float* __restrict__ b2v, float* __restrict__ h2o)
{
    __shared__ float As[16][260];
    __shared__ float Bs[16][260];
    __shared__ float red[16][17];
    int t = threadIdx.x;
    int m0 = blockIdx.x * 16;
    {
        int rr = t >> 4, c4 = (t & 15) * 4;
        int row = m0 + rr;
#pragma unroll
        for (int i = 0; i < 4; ++i) {
            int c = c4 + i * 64;
            float4 x = make_float4(0.f, 0.f, 0.f, 0.f);
            if (row < NPOS) x = *(const float4*)(outb + (size_t)row * OUTF + c);
            *(float4*)&As[rr][c] = x;
        }
    }
    int q = t & 15, dg = (t >> 4) * 16;
    float acc[16];
#pragma unroll
    for (int i = 0; i < 16; ++i) acc[i] = 0.f;
    for (int k0 = 0; k0 < 256; k0 += 16) {
        __syncthreads();
        {
            int kk = t >> 4, n16 = (t & 15) * 16;
#pragma unroll
            for (int i = 0; i < 4; ++i) {
                float4 x = *(const float4*)(w1 + (size_t)(k0 + kk) * OUTF + n16 + i * 4);
                *(float4*)&Bs[kk][n16 + i * 4] = x;
            }
        }
        __syncthreads();
#pragma unroll
        for (int kk = 0; kk < 16; ++kk) {
            float a = As[q][k0 + kk];
#pragma unroll
            for (int i = 0; i < 16; i += 4) {
                float4 b = *(const float4*)&Bs[kk][dg + i];
                acc[i + 0] += a * b.x; acc[i + 1] += a * b.y;
                acc[i + 2] += a * b.z; acc[i + 3] += a * b.w;
            }
        }
    }
    float x[16];
#pragma unroll
    for (int i = 0; i < 16; ++i) x[i] = acc[i] + b1v[dg + i];
    float ps = 0.f;
#pragma unroll
    for (int i = 0; i < 16; ++i) ps += x[i];
    __syncthreads();
    red[t >> 4][q] = ps;
    __syncthreads();
    float s = 0.f;
#pragma unroll
    for (int i = 0; i < 16; ++i) s += red[i][q];
    float mu = s * (1.0f / 256.0f);
    float pv = 0.f;
#pragma unroll
    for (int i = 0; i < 16; ++i) { float d = x[i] - mu; pv += d * d; }
    __syncthreads();
    red[t >> 4][q] = pv;
    __syncthreads();
    float v = 0.f;
#pragma unroll
    for (int i = 0; i < 16; ++i) v += red[i][q];
    float rs = rsqrtf(v * (1.0f / 256.0f) + 1e-6f);
    int row = m0 + q;
    if (row < NPOS) {
#pragma unroll
        for (int i = 0; i < 16; ++i) {
            int n = dg + i;
            h2o[(size_t)row * OUTF + n] = tanhf((x[i] - mu) * rs * g2[n] + b2v[n]);
        }
    }
}

// ---------------------------------------------------------------------------
// E4: final = h2 @ w2  (no bias) -> d_out
// ---------------------------------------------------------------------------
__global__ __launch_bounds__(256) void e4_final(
    const float* __restrict__ h2in, const float* __restrict__ w2,
    float* __restrict__ outp)
{
    __shared__ float AT[16][68];
    __shared__ float Bs[16][132];
    int t = threadIdx.x;
    int n0 = blockIdx.x * 128;
    int m0 = blockIdx.y * 64;
    float acc[4][8];
#pragma unroll
    for (int i = 0; i < 4; ++i)
#pragma unroll
        for (int j = 0; j < 8; ++j) acc[i][j] = 0.f;
    int mg = (t >> 4) * 4, jg = (t & 15) * 8;
    int am = t & 63, ak = (t >> 6) * 4;
    int bkk = t >> 4, bn = (t & 15) * 8;
    for (int k0 = 0; k0 < 256; k0 += 16) {
        __syncthreads();
        {
            int row = m0 + am;
            float4 v = make_float4(0.f, 0.f, 0.f, 0.f);
            if (row < NPOS) v = *(const float4*)(h2in + (size_t)row * OUTF + k0 + ak);
            AT[ak + 0][am] = v.x; AT[ak + 1][am] = v.y;
            AT[ak + 2][am] = v.z; AT[ak + 3][am] = v.w;
        }
        {
            const float* p = w2 + (size_t)(k0 + bkk) * OUTF + n0 + bn;
            float4 u0 = *(const float4*)p;
            float4 u1 = *(const float4*)(p + 4);
            *(float4*)&Bs[bkk][bn]     = u0;
            *(float4*)&Bs[bkk][bn + 4] = u1;
        }
        __syncthreads();
#pragma unroll
        for (int kk = 0; kk < 16; ++kk) {
            float4 a  = *(const float4*)&AT[kk][mg];
            float4 b0 = *(const float4*)&Bs[kk][jg];
            float4 b1 = *(const float4*)&Bs[kk][jg + 4];
            float av[4] = {a.x, a.y, a.z, a.w};
            float bv_[8] = {b0.x, b0.y, b0.z, b0.w, b1.x, b1.y, b1.z, b1.w};
#pragma unroll
            for (int i = 0; i < 4; ++i)
#pragma unroll
                for (int j = 0; j < 8; ++j) acc[i][j] += av[i] * bv_[j];
        }
    }
#pragma unroll
    for (int i = 0; i < 4; ++i) {
        int row = m0 + mg + i;
        if (row < NPOS) {
#pragma unroll
            for (int j = 0; j < 8; ++j) {
                outp[(size_t)row * OUTF + n0 + jg + j] = acc[i][j];
            }
        }
    }
}

// ---------------------------------------------------------------------------
extern "C" void kernel_launch(void* const* d_in, const int* in_sizes, int n_in,
                              void* d_out, int out_size, void* d_ws, size_t ws_size,
                              hipStream_t stream)
{
    const float* feature = (const float*)d_in[0];
    const float* adj   = (const float*)d_in[1];
    const float* r     = (const float*)d_in[2];
    const float* Wq    = (const float*)d_in[3];
    const float* bq    = (const float*)d_in[4];
    const float* Wk    = (const float*)d_in[5];
    const float* bk    = (const float*)d_in[6];
    const float* Wv    = (const float*)d_in[7];
    const float* bv    = (const float*)d_in[8];
    const float* Ww    = (const float*)d_in[9];
    const float* bw    = (const float*)d_in[10];
    const float* Wr    = (const float*)d_in[11];
    const float* br    = (const float*)d_in[12];
    const float* Wbeta = (const float*)d_in[13];
    const float* bbeta = (const float*)d_in[14];
    const float* ln1g  = (const float*)d_in[15];
    const float* ln1b  = (const float*)d_in[16];
    const float* w1    = (const float*)d_in[17];
    const float* b1    = (const float*)d_in[18];
    const float* ln2g  = (const float*)d_in[19];
    const float* ln2b  = (const float*)d_in[20];
    const float* w2    = (const float*)d_in[21];
    const int*   flag  = (const int*)d_in[22];
    float* out = (float*)d_out;

    // --- workspace layout (liveness-aliased) ---
    // k2 phase: P1 (3 part1 chunks, 30,105,600 B) aliases LG region;
    //           P0 (part0 chunk, 10,035,200 B) aliases mpart region.
    // Both are dead once k2_reduce produces Bhi/Blo, before k3/k3b write them.
    char* ws = (char*)d_ws;
    float*          LG    = (float*)(ws + 0);            // 30,105,600
    float*          P1    = (float*)(ws + 0);
    float*          hQ    = (float*)(ws + 30130176);
    float*          hK    = (float*)(ws + 35147776);
    float*          cc    = (float*)(ws + 30130176);
    float*          hV    = (float*)(ws + 40165376);
    float*          outb  = (float*)(ws + 40165376);
    float*          Hb    = (float*)(ws + 45182976);
    float*          hh2   = (float*)(ws + 45182976);
    unsigned short* Bhi   = (unsigned short*)(ws + 50200576);  // 10,043,392
    unsigned short* Blo   = (unsigned short*)(ws + 60243968);  // 10,043,392
    float*          mpart = (float*)(ws + 70287360);
    float*          P0    = (float*)(ws + 70287360);
    float*          S     = (float*)(ws + 80322560);

    k0_rp<<<1, 256, 0, stream>>>(r, Wr, br, flag, S);
    k1_proj<<<dim3(8, 77), 256, 0, stream>>>(feature, Wq, bq, Wk, bk, Wv, bv, Ww, bw,
                                             hQ, hK, hV, Hb);
    k2_mfma<<<dim3(77, 4, 4), 256, 0, stream>>>(hK, adj, S, P0, P1);
    k2_reduce<<<dim3(20, 8, 8), 256, 0, stream>>>(P0, P1, Bhi, Blo);
    for (int s = 0; s < NSLAB; ++s) {
        int j0 = s * JS;
        k3a_mfma<<<dim3(3, 156), 256, 0, stream>>>(hQ, S, Bhi, Blo, LG, j0);
        k3b_pv<<<dim3(154, 2), 256, 0, stream>>>(LG, hV, mpart, j0, s == 0 ? 1 : 0);
    }
    e1_relu_ln<<<1225, 256, 0, stream>>>(mpart, Hb, ln1g, ln1b, cc);
    e2_beta<<<dim3(2, 77), 256, 0, stream>>>(cc, Wbeta, bbeta, outb);
    e3_w1_ln2<<<307, 256, 0, stream>>>(outb, w1, b1, ln2g, ln2b, hh2);
    e4_final<<<dim3(2, 77), 256, 0, stream>>>(hh2, w2, out);
}